// Round 1
// baseline (2224.379 us; speedup 1.0000x reference)
//
#include <hip/hip_runtime.h>
#include <hip/hip_bf16.h>
#include <cstdint>
#include <cstddef>

// SNN: B=16384, D_IN=512, H0=1024, H1=512, T=8
// out[i] = b3 + (1/8) * sum_n w3[n] * popcount(spk2_pattern[i][n])
//
// K1: cur1 = data@w1^T + b1 (f32 GEMM), fused LIF1 (beta=1.0) -> 8-bit spike
//     pattern per element, packed uint8 [16384][1024] in d_ws.
// K2: 8 simultaneous GEMM accumulations (one per time step) with binary A
//     from the packed patterns; fused LIF2 (beta=0.95) + popcount*w3 row
//     reduction epilogue -> atomicAdd into out (pre-initialized to b3).
//
// Numerics: pure f32, sequential-K accumulation; LIF recurrences use
// __fmul_rn/__fadd_rn/__fsub_rn to forbid fma contraction so elementwise ops
// round exactly like the jnp/np reference's separate mul/add/sub.

#define NB 16384
#define DIN 512
#define NH0 1024
#define NH1 512

__global__ void init_out_kernel(float* __restrict__ out,
                                const float* __restrict__ b3, int n) {
    int i = blockIdx.x * blockDim.x + threadIdx.x;
    if (i < n) out[i] = b3[0];
}

// ---------------- K1: GEMM1 + LIF1 -> packed spike patterns ----------------
__global__ __launch_bounds__(256) void gemm1_spike_kernel(
    const float* __restrict__ data, const float* __restrict__ w1,
    const float* __restrict__ b1, uint8_t* __restrict__ pat)
{
    __shared__ float As[64][68];  // pad 68: row stride 4 banks -> conflict-free ty reads
    __shared__ float Bs[64][68];
    const int tid = threadIdx.x;
    const int tx = tid & 15, ty = tid >> 4;
    const int i0 = blockIdx.x * 64, n0 = blockIdx.y * 64;

    float acc[4][4] = {};

    for (int kb = 0; kb < DIN; kb += 64) {
        // stage A (data) and B (w1) tiles: 64x64 f32 each, float4 loads
        #pragma unroll
        for (int rep = 0; rep < 4; ++rep) {
            int idx = tid + rep * 256;
            int row = idx >> 4, c4 = (idx & 15) * 4;
            float4 va = *(const float4*)(data + (size_t)(i0 + row) * DIN + kb + c4);
            *(float4*)(&As[row][c4]) = va;
            float4 vb = *(const float4*)(w1 + (size_t)(n0 + row) * DIN + kb + c4);
            *(float4*)(&Bs[row][c4]) = vb;
        }
        __syncthreads();
        #pragma unroll 4
        for (int k4 = 0; k4 < 16; ++k4) {
            float4 a4[4], b4[4];
            #pragma unroll
            for (int ii = 0; ii < 4; ++ii)
                a4[ii] = *(const float4*)(&As[ty + ii * 16][k4 * 4]);
            #pragma unroll
            for (int nn = 0; nn < 4; ++nn)
                b4[nn] = *(const float4*)(&Bs[tx + nn * 16][k4 * 4]);
            #pragma unroll
            for (int ii = 0; ii < 4; ++ii) {
                #pragma unroll
                for (int nn = 0; nn < 4; ++nn) {
                    acc[ii][nn] = fmaf(a4[ii].x, b4[nn].x, acc[ii][nn]);
                    acc[ii][nn] = fmaf(a4[ii].y, b4[nn].y, acc[ii][nn]);
                    acc[ii][nn] = fmaf(a4[ii].z, b4[nn].z, acc[ii][nn]);
                    acc[ii][nn] = fmaf(a4[ii].w, b4[nn].w, acc[ii][nn]);
                }
            }
        }
        __syncthreads();
    }

    // LIF1: beta=1.0; reset on OLD mem; spike = (mem_new - 1 > 0) == mem_new > 1
    #pragma unroll
    for (int ii = 0; ii < 4; ++ii) {
        int i = i0 + ty + ii * 16;
        #pragma unroll
        for (int nn = 0; nn < 4; ++nn) {
            int n = n0 + tx + nn * 16;
            float x = __fadd_rn(acc[ii][nn], b1[n]);
            float mem = 0.0f;
            unsigned p = 0;
            #pragma unroll
            for (int t = 0; t < 8; ++t) {
                bool reset = mem > 1.0f;
                float tmp = __fadd_rn(mem, x);          // 1.0*mem + cur1
                mem = reset ? __fsub_rn(tmp, 1.0f) : tmp;
                p |= (mem > 1.0f ? 1u : 0u) << t;
            }
            pat[(size_t)i * NH0 + n] = (uint8_t)p;
        }
    }
}

// ---------- K2: 8x GEMM (binary A) + LIF2 + popcount*w3 reduction ----------
__global__ __launch_bounds__(256) void gemm2_lif_out_kernel(
    const uint8_t* __restrict__ pat, const float* __restrict__ w2,
    const float* __restrict__ b2, const float* __restrict__ w3,
    float* __restrict__ out)
{
    __shared__ float Bs[64][68];     // w2 tile [n][k]
    __shared__ uint8_t Ap[64][80];   // pattern tile [i][k], 80B rows: 16B-aligned writes
    __shared__ float red[64][17];

    const int tid = threadIdx.x;
    const int tx = tid & 15, ty = tid >> 4;
    const int i0 = blockIdx.x * 64, n0 = blockIdx.y * 64;

    float acc[8][4][4] = {};   // [t][ii][nn]

    for (int kb = 0; kb < NH0; kb += 64) {
        #pragma unroll
        for (int rep = 0; rep < 4; ++rep) {
            int idx = tid + rep * 256;
            int row = idx >> 4, c4 = (idx & 15) * 4;
            float4 vb = *(const float4*)(w2 + (size_t)(n0 + row) * NH0 + kb + c4);
            *(float4*)(&Bs[row][c4]) = vb;
        }
        {
            int row = tid >> 2, c16 = (tid & 3) * 16;
            uint4 v = *(const uint4*)(pat + (size_t)(i0 + row) * NH0 + kb + c16);
            *(uint4*)(&Ap[row][c16]) = v;
        }
        __syncthreads();
        #pragma unroll 2
        for (int kk = 0; kk < 64; ++kk) {
            float w[4];
            #pragma unroll
            for (int nn = 0; nn < 4; ++nn) w[nn] = Bs[tx + nn * 16][kk];
            #pragma unroll
            for (int ii = 0; ii < 4; ++ii) {
                unsigned p = Ap[ty + ii * 16][kk];
                #pragma unroll
                for (int t = 0; t < 8; ++t) {
                    float m = (float)((p >> t) & 1u);
                    #pragma unroll
                    for (int nn = 0; nn < 4; ++nn)
                        acc[t][ii][nn] = fmaf(m, w[nn], acc[t][ii][nn]);
                }
            }
        }
        __syncthreads();
    }

    // LIF2 (beta=0.95, reset on old mem) + spike popcount * w3
    #pragma unroll
    for (int ii = 0; ii < 4; ++ii) {
        float s = 0.0f;
        #pragma unroll
        for (int nn = 0; nn < 4; ++nn) {
            int n = n0 + tx + nn * 16;
            float b2n = b2[n];
            float mem = 0.0f;
            int pc = 0;
            #pragma unroll
            for (int t = 0; t < 8; ++t) {
                bool reset = mem > 1.0f;
                float x = __fadd_rn(acc[t][ii][nn], b2n);   // cur2 = gemm + b2
                float bm = __fmul_rn(0.95f, mem);           // beta2*mem
                float tmp = __fadd_rn(bm, x);
                mem = reset ? __fsub_rn(tmp, 1.0f) : tmp;
                pc += (mem > 1.0f) ? 1 : 0;
            }
            s = fmaf(w3[n], (float)pc, s);
        }
        red[ty + ii * 16][tx] = s;
    }
    __syncthreads();
    if (tid < 64) {
        float s = 0.0f;
        #pragma unroll
        for (int j = 0; j < 16; ++j) s += red[tid][j];
        atomicAdd(&out[i0 + tid], 0.125f * s);
    }
}

extern "C" void kernel_launch(void* const* d_in, const int* in_sizes, int n_in,
                              void* d_out, int out_size, void* d_ws, size_t ws_size,
                              hipStream_t stream) {
    const float* data = (const float*)d_in[0];
    const float* w1   = (const float*)d_in[1];
    const float* b1   = (const float*)d_in[2];
    const float* w2   = (const float*)d_in[3];
    const float* b2   = (const float*)d_in[4];
    const float* w3   = (const float*)d_in[5];
    const float* b3   = (const float*)d_in[6];
    float* out = (float*)d_out;
    uint8_t* pat = (uint8_t*)d_ws;   // [16384][1024] packed spk1 patterns, 16 MB

    init_out_kernel<<<(NB + 255) / 256, 256, 0, stream>>>(out, b3, NB);
    gemm1_spike_kernel<<<dim3(NB / 64, NH0 / 64), 256, 0, stream>>>(data, w1, b1, pat);
    gemm2_lif_out_kernel<<<dim3(NB / 64, NH1 / 64), 256, 0, stream>>>(pat, w2, b2, w3, out);
}

// Round 3
// 607.220 us; speedup vs baseline: 3.6632x; 3.6632x over previous
//
#include <hip/hip_runtime.h>
#include <hip/hip_bf16.h>
#include <cstdint>
#include <cstddef>

// SNN: B=16384, D_IN=512, H0=1024, H1=512, T=8
// out[i] = b3 + (1/8) * sum_n w3[n] * popcount(spk2_pattern[i][n])
//
// K1: cur1 = data@w1^T + b1 (f32 VALU GEMM), fused LIF1 (beta=1.0) -> packed
//     uint8 spike patterns [16384][1024] in d_ws.  BYTE-IDENTICAL to the
//     passing round-1 kernel (spk1 flips are high-sensitivity; don't touch).
// K2: MFMA. 8 simultaneous bf16 MFMA GEMM accumulations (one per time step).
//     A = spike bits expanded in-register to bf16 {0,1} via v_perm LUT.
//     B = w2 split into bf16 hi+mid+lo (residual ~|w|*2^-27, negligible) ->
//     3 MFMAs per A-frag, f32 accumulate, largest-first ordering.
//     Fused LIF2 + popcount*w3 row reduction -> atomicAdd into out(=b3).
//
// Elementwise LIF math uses __fmul_rn/__fadd_rn/__fsub_rn (no fma contraction)
// so per-step rounding mirrors the jnp/np reference's separate mul/add/sub.

#define NB 16384
#define DIN 512
#define NH0 1024
#define NH1 512

typedef float f32x4 __attribute__((ext_vector_type(4)));
typedef short bf16x8 __attribute__((ext_vector_type(8)));

__global__ void init_out_kernel(float* __restrict__ out,
                                const float* __restrict__ b3, int n) {
    int i = blockIdx.x * blockDim.x + threadIdx.x;
    if (i < n) out[i] = b3[0];
}

// ---------------- K1: GEMM1 + LIF1 -> packed spike patterns ----------------
__global__ __launch_bounds__(256) void gemm1_spike_kernel(
    const float* __restrict__ data, const float* __restrict__ w1,
    const float* __restrict__ b1, uint8_t* __restrict__ pat)
{
    __shared__ float As[64][68];
    __shared__ float Bs[64][68];
    const int tid = threadIdx.x;
    const int tx = tid & 15, ty = tid >> 4;
    const int i0 = blockIdx.x * 64, n0 = blockIdx.y * 64;

    float acc[4][4] = {};

    for (int kb = 0; kb < DIN; kb += 64) {
        #pragma unroll
        for (int rep = 0; rep < 4; ++rep) {
            int idx = tid + rep * 256;
            int row = idx >> 4, c4 = (idx & 15) * 4;
            float4 va = *(const float4*)(data + (size_t)(i0 + row) * DIN + kb + c4);
            *(float4*)(&As[row][c4]) = va;
            float4 vb = *(const float4*)(w1 + (size_t)(n0 + row) * DIN + kb + c4);
            *(float4*)(&Bs[row][c4]) = vb;
        }
        __syncthreads();
        #pragma unroll 4
        for (int k4 = 0; k4 < 16; ++k4) {
            float4 a4[4], b4[4];
            #pragma unroll
            for (int ii = 0; ii < 4; ++ii)
                a4[ii] = *(const float4*)(&As[ty + ii * 16][k4 * 4]);
            #pragma unroll
            for (int nn = 0; nn < 4; ++nn)
                b4[nn] = *(const float4*)(&Bs[tx + nn * 16][k4 * 4]);
            #pragma unroll
            for (int ii = 0; ii < 4; ++ii) {
                #pragma unroll
                for (int nn = 0; nn < 4; ++nn) {
                    acc[ii][nn] = fmaf(a4[ii].x, b4[nn].x, acc[ii][nn]);
                    acc[ii][nn] = fmaf(a4[ii].y, b4[nn].y, acc[ii][nn]);
                    acc[ii][nn] = fmaf(a4[ii].z, b4[nn].z, acc[ii][nn]);
                    acc[ii][nn] = fmaf(a4[ii].w, b4[nn].w, acc[ii][nn]);
                }
            }
        }
        __syncthreads();
    }

    #pragma unroll
    for (int ii = 0; ii < 4; ++ii) {
        int i = i0 + ty + ii * 16;
        #pragma unroll
        for (int nn = 0; nn < 4; ++nn) {
            int n = n0 + tx + nn * 16;
            float x = __fadd_rn(acc[ii][nn], b1[n]);
            float mem = 0.0f;
            unsigned p = 0;
            #pragma unroll
            for (int t = 0; t < 8; ++t) {
                bool reset = mem > 1.0f;
                float tmp = __fadd_rn(mem, x);
                mem = reset ? __fsub_rn(tmp, 1.0f) : tmp;
                p |= (mem > 1.0f ? 1u : 0u) << t;
            }
            pat[(size_t)i * NH0 + n] = (uint8_t)p;
        }
    }
}

// ------ K2: MFMA 8x GEMM (binary A, 3-way-split-bf16 B) + LIF2 + out -------
__device__ inline uint16_t f2bf(float f) {
    __hip_bfloat16 h = __float2bfloat16(f);
    return *reinterpret_cast<uint16_t*>(&h);
}
__device__ inline float bf2f(uint16_t u) {
    __hip_bfloat16 h = *reinterpret_cast<__hip_bfloat16*>(&u);
    return __bfloat162float(h);
}

__global__ __launch_bounds__(256, 2) void gemm2_mfma_kernel(
    const uint8_t* __restrict__ pat, const float* __restrict__ w2,
    const float* __restrict__ b2, const float* __restrict__ w3,
    float* __restrict__ out)
{
    // LDS: w2 tile as bf16 hi/mid/lo [64 n][64 k] stride 72 (144B rows),
    //      pattern tile [64 i][64 k] bytes, stride 80 (16B-mult).
    __shared__ __align__(16) uint16_t Bhi[64][72];
    __shared__ __align__(16) uint16_t Bmd[64][72];
    __shared__ __align__(16) uint16_t Blo[64][72];
    __shared__ __align__(16) uint8_t  Ap[64][80];

    const int tid  = threadIdx.x;
    const int lane = tid & 63;
    const int wv   = tid >> 6;       // wave 0..3: i-rows [wv*16, wv*16+16)
    const int lr   = lane & 15;      // A-row / B-col within fragment
    const int lg   = lane >> 4;      // k-group 0..3 (8 consecutive k each)
    const int i0   = blockIdx.x * 64, n0 = blockIdx.y * 64;

    f32x4 acc[8][4];                 // [t][nfrag]
    #pragma unroll
    for (int t = 0; t < 8; ++t)
        #pragma unroll
        for (int nf = 0; nf < 4; ++nf)
            acc[t][nf] = (f32x4)(0.0f);

    const int srow = tid >> 2;            // 0..63
    const int scol = (tid & 3) * 16;      // 0,16,32,48

    for (int kb = 0; kb < NH0; kb += 64) {
        __syncthreads();
        // --- stage w2 tile f32 -> bf16 hi/mid/lo ---
        const float* wsrc = w2 + (size_t)(n0 + srow) * NH0 + kb + scol;
        #pragma unroll
        for (int g = 0; g < 2; ++g) {
            float4 f0 = *(const float4*)(wsrc + g * 8);
            float4 f1 = *(const float4*)(wsrc + g * 8 + 4);
            float f[8] = {f0.x, f0.y, f0.z, f0.w, f1.x, f1.y, f1.z, f1.w};
            uint32_t hw[4], mw[4], lw[4];
            #pragma unroll
            for (int e = 0; e < 4; ++e) {
                float a = f[2 * e], b = f[2 * e + 1];
                uint16_t h0 = f2bf(a), h1 = f2bf(b);
                float d0 = __fsub_rn(a, bf2f(h0));
                float d1 = __fsub_rn(b, bf2f(h1));
                uint16_t m0 = f2bf(d0), m1 = f2bf(d1);
                float e0 = __fsub_rn(d0, bf2f(m0));
                float e1 = __fsub_rn(d1, bf2f(m1));
                uint16_t l0 = f2bf(e0), l1 = f2bf(e1);
                hw[e] = (uint32_t)h0 | ((uint32_t)h1 << 16);
                mw[e] = (uint32_t)m0 | ((uint32_t)m1 << 16);
                lw[e] = (uint32_t)l0 | ((uint32_t)l1 << 16);
            }
            *(uint4*)(&Bhi[srow][scol + g * 8]) = make_uint4(hw[0], hw[1], hw[2], hw[3]);
            *(uint4*)(&Bmd[srow][scol + g * 8]) = make_uint4(mw[0], mw[1], mw[2], mw[3]);
            *(uint4*)(&Blo[srow][scol + g * 8]) = make_uint4(lw[0], lw[1], lw[2], lw[3]);
        }
        // --- stage pattern tile ---
        {
            uint4 pv = *(const uint4*)(pat + (size_t)(i0 + srow) * NH0 + kb + scol);
            *(uint4*)(&Ap[srow][scol]) = pv;
        }
        __syncthreads();

        // --- compute: 2 k32-substeps ---
        #pragma unroll
        for (int s = 0; s < 2; ++s) {
            const int k0 = s * 32;
            bf16x8 bh[4], bm[4], bl[4];
            #pragma unroll
            for (int nf = 0; nf < 4; ++nf) {
                const int col = nf * 16 + lr;
                bh[nf] = *(const bf16x8*)(&Bhi[col][k0 + lg * 8]);
                bm[nf] = *(const bf16x8*)(&Bmd[col][k0 + lg * 8]);
                bl[nf] = *(const bf16x8*)(&Blo[col][k0 + lg * 8]);
            }
            const uint2 p8 = *(const uint2*)(&Ap[wv * 16 + lr][k0 + lg * 8]);
            #pragma unroll
            for (int t = 0; t < 8; ++t) {
                // expand bit t of 8 pattern bytes -> 8 bf16 {0,1}
                uint32_t y0 = (p8.x >> t) & 0x01010101u;
                uint32_t y1 = (p8.y >> t) & 0x01010101u;
                uint32_t s0 = __builtin_amdgcn_perm(0u, y0, 0x01010000u) | 0x02000200u;
                uint32_t s1 = __builtin_amdgcn_perm(0u, y0, 0x03030202u) | 0x02000200u;
                uint32_t s2 = __builtin_amdgcn_perm(0u, y1, 0x01010000u) | 0x02000200u;
                uint32_t s3 = __builtin_amdgcn_perm(0u, y1, 0x03030202u) | 0x02000200u;
                union { uint4 u; bf16x8 v; } af;
                af.u = make_uint4(__builtin_amdgcn_perm(0u, 0x3F008000u, s0),
                                  __builtin_amdgcn_perm(0u, 0x3F008000u, s1),
                                  __builtin_amdgcn_perm(0u, 0x3F008000u, s2),
                                  __builtin_amdgcn_perm(0u, 0x3F008000u, s3));
                #pragma unroll
                for (int nf = 0; nf < 4; ++nf) {
                    acc[t][nf] = __builtin_amdgcn_mfma_f32_16x16x32_bf16(
                        af.v, bh[nf], acc[t][nf], 0, 0, 0);
                    acc[t][nf] = __builtin_amdgcn_mfma_f32_16x16x32_bf16(
                        af.v, bm[nf], acc[t][nf], 0, 0, 0);
                    acc[t][nf] = __builtin_amdgcn_mfma_f32_16x16x32_bf16(
                        af.v, bl[nf], acc[t][nf], 0, 0, 0);
                }
            }
        }
    }

    // --- LIF2 + popcount*w3 ---
    // C layout (m89-verified): col = lane&15, row = (lane>>4)*4 + reg
    float rowsum[4] = {0.0f, 0.0f, 0.0f, 0.0f};
    #pragma unroll
    for (int nf = 0; nf < 4; ++nf) {
        const int n = n0 + nf * 16 + lr;
        const float b2n = b2[n];
        const float w3n = w3[n];
        #pragma unroll
        for (int r = 0; r < 4; ++r) {
            float mem = 0.0f;
            int pc = 0;
            #pragma unroll
            for (int t = 0; t < 8; ++t) {
                bool reset = mem > 1.0f;
                float x   = __fadd_rn(acc[t][nf][r], b2n);
                float tmp = __fadd_rn(__fmul_rn(0.95f, mem), x);
                mem = reset ? __fsub_rn(tmp, 1.0f) : tmp;
                pc += (mem > 1.0f) ? 1 : 0;
            }
            rowsum[r] = fmaf(w3n, (float)pc, rowsum[r]);
        }
    }
    // reduce across the 16 lanes sharing lg (lane bits 0-3), then atomic
    #pragma unroll
    for (int r = 0; r < 4; ++r) {
        float s = rowsum[r];
        s += __shfl_xor(s, 1);
        s += __shfl_xor(s, 2);
        s += __shfl_xor(s, 4);
        s += __shfl_xor(s, 8);
        if (lr == 0)
            atomicAdd(&out[i0 + wv * 16 + lg * 4 + r], 0.125f * s);
    }
}

extern "C" void kernel_launch(void* const* d_in, const int* in_sizes, int n_in,
                              void* d_out, int out_size, void* d_ws, size_t ws_size,
                              hipStream_t stream) {
    const float* data = (const float*)d_in[0];
    const float* w1   = (const float*)d_in[1];
    const float* b1   = (const float*)d_in[2];
    const float* w2   = (const float*)d_in[3];
    const float* b2   = (const float*)d_in[4];
    const float* w3   = (const float*)d_in[5];
    const float* b3   = (const float*)d_in[6];
    float* out = (float*)d_out;
    uint8_t* pat = (uint8_t*)d_ws;   // [16384][1024] packed spk1 patterns, 16 MB

    init_out_kernel<<<(NB + 255) / 256, 256, 0, stream>>>(out, b3, NB);
    gemm1_spike_kernel<<<dim3(NB / 64, NH0 / 64), 256, 0, stream>>>(data, w1, b1, pat);
    gemm2_mfma_kernel<<<dim3(NB / 64, NH1 / 64), 256, 0, stream>>>(pat, w2, b2, w3, out);
}